// Round 4
// baseline (541.152 us; speedup 1.0000x reference)
//
#include <hip/hip_runtime.h>
#include <math.h>

#define NN 8192
#define EE 131072
#define CC 64
#define GG 32
#define NEL 10

__device__ __forceinline__ float silu_f(float x) { return x / (1.0f + __expf(-x)); }

// stage a 64x64 row-major matrix W[c][d] into LDS transposed+XOR-swizzled:
// float4 slot (d*16 + (c4 ^ (d&15))) holds (W[4c4+0][d], ..., W[4c4+3][d])
__device__ __forceinline__ void stage_wT(const float* __restrict__ W, float* sWT, int tid) {
    for (int idx = tid; idx < 4096; idx += 256) {
        int d = idx & 63, c = idx >> 6;
        sWT[(d << 6) + ((((c >> 2) ^ (d & 15)) << 2) | (c & 3))] = W[idx];
    }
}
#define WREAD(sWT, d, c4) (((const float4*)(sWT))[((d) << 4) + ((c4) ^ ((d) & 15))])
#define DOT4(a, b) ((a).x * (b).x + (a).y * (b).y + (a).z * (b).z + (a).w * (b).w)

// ---------------- h0 = W_embed[elem] ; elem = argmax(node_attrs) --------------------
__global__ __launch_bounds__(256) void k_h0(const float* __restrict__ na,
                                            const float* __restrict__ Wemb,
                                            float* __restrict__ h0,
                                            int* __restrict__ elem) {
    int n = blockIdx.x * 4 + (threadIdx.x >> 6);
    int d = threadIdx.x & 63;
    float acc = 0.0f;
    float best = -1.0f; int bi = 0;
    #pragma unroll
    for (int k = 0; k < NEL; k++) {
        float a = na[n * NEL + k];
        acc += a * Wemb[k * 64 + d];
        if (a > best) { best = a; bi = k; }
    }
    h0[n * 64 + d] = acc;
    if (d == 0) elem[n] = bi;
}

// ---------------- sc1 lookup table: sc1tab[e] = W_embed[e] @ Wsc1[e] ----------------
__global__ __launch_bounds__(64) void k_sc1tab(const float* __restrict__ Wemb,
                                               const float* __restrict__ Wsc1,
                                               float* __restrict__ tab) {
    int e = blockIdx.x, d = threadIdx.x;
    float acc = 0.0f;
    for (int c = 0; c < 64; c++)
        acc += Wemb[e * 64 + c] * Wsc1[e * 4096 + c * 64 + d];
    tab[e * 64 + d] = acc;
}

// ---------------- element bucketing -------------------------------------------------
__global__ __launch_bounds__(256) void k_count(const int* __restrict__ elem, int* cnt) {
    int n = blockIdx.x * 256 + threadIdx.x;
    atomicAdd(&cnt[elem[n]], 1);
}
__global__ void k_offsets(const int* __restrict__ cnt, int* offs, int* cursor) {
    if (threadIdx.x == 0) {
        int s = 0;
        for (int e = 0; e < NEL; e++) { offs[e] = s; cursor[e] = s; s += cnt[e]; }
    }
}
__global__ __launch_bounds__(256) void k_fill(const int* __restrict__ elem,
                                              int* cursor, int* __restrict__ order) {
    int n = blockIdx.x * 256 + threadIdx.x;
    int p = atomicAdd(&cursor[elem[n]], 1);
    order[p] = n;
}

// ---------------- tiled edge kernel (unchanged from round 2) ------------------------
__global__ __launch_bounds__(256) void edge_tile(
    const float* __restrict__ feats, const float* __restrict__ pos,
    const float* __restrict__ shifts, const int* __restrict__ eidx,
    const float* __restrict__ Wra, const float* __restrict__ Wrb,
    float* __restrict__ A)
{
    __shared__ float smem[13760];
    __shared__ int   sSnd[64], sRcv[64], sLive[64];
    float* sWaT  = smem;
    float* sWbT  = smem + 512;
    float* sMsg  = smem;
    float* sRb   = smem + 8704;
    float* sHidT = smem + 9216;
    float* sU    = smem + 13568;

    int tid = threadIdx.x;
    int e_base = blockIdx.x * 64;

    if (tid < 64) {
        int e = e_base + tid;
        int snd = eidx[e];
        int rcv = eidx[EE + e];
        float vx = pos[rcv * 3 + 0] - pos[snd * 3 + 0] + shifts[e * 3 + 0];
        float vy = pos[rcv * 3 + 1] - pos[snd * 3 + 1] + shifts[e * 3 + 1];
        float vz = pos[rcv * 3 + 2] - pos[snd * 3 + 2] + shifts[e * 3 + 2];
        float r = sqrtf(vx * vx + vy * vy + vz * vz + 1e-12f);
        float rinv = 1.0f / r;
        float x = r * 0.2f;
        int live = x < 1.0f;
        float pref = 0.0f;
        if (live) {
            float x2 = x * x, x4 = x2 * x2, x5 = x4 * x;
            float env = 1.0f - 21.0f * x5 + 35.0f * x5 * x - 15.0f * x5 * x2;
            pref = 0.632455532033676f * rinv * env;
        }
        float s1, c1;
        __sincosf(0.62831853071795865f * r, &s1, &c1);
        float k2c = 2.0f * c1;
        float sp = 0.0f, sn = s1;
        #pragma unroll
        for (int b = 0; b < 8; b++) {
            sRb[b * 64 + tid] = pref * sn;
            float t = k2c * sn - sp; sp = sn; sn = t;
        }
        sU[tid]       = vx * rinv;
        sU[64 + tid]  = vy * rinv;
        sU[128 + tid] = vz * rinv;
        sSnd[tid] = snd; sRcv[tid] = rcv; sLive[tid] = live;
    }
    for (int idx = tid; idx < 512; idx += 256) {
        int b = idx >> 6, j = idx & 63;
        sWaT[j * 8 + b] = Wra[idx];
    }
    for (int idx = tid; idx < 64 * 128; idx += 256) {
        int j = idx >> 7, c = idx & 127;
        float v = Wrb[j * 256 + c] * (c < 64 ? 0.0625f : 0.10825317547305482f);
        int jb = j >> 2, jl = j & 3;
        int sj = ((jb ^ ((c >> 3) & 7)) << 2) | jl;
        sWbT[c * 64 + sj] = v;
    }
    __syncthreads();

    {
        int e = tid & 63, jg = tid >> 6;
        float rbv[8];
        #pragma unroll
        for (int b = 0; b < 8; b++) rbv[b] = sRb[b * 64 + e];
        const float4* waT4 = (const float4*)sWaT;
        float hid[16];
        #pragma unroll
        for (int jj = 0; jj < 16; jj++) {
            int j = jg * 16 + jj;
            float4 wa0 = waT4[j * 2 + 0];
            float4 wa1 = waT4[j * 2 + 1];
            float acc = rbv[0] * wa0.x + rbv[1] * wa0.y + rbv[2] * wa0.z + rbv[3] * wa0.w
                      + rbv[4] * wa1.x + rbv[5] * wa1.y + rbv[6] * wa1.z + rbv[7] * wa1.w;
            hid[jj] = silu_f(acc);
        }
        float4* hidT4 = (float4*)sHidT;
        int hk = (e >> 1) & 7;
        #pragma unroll
        for (int q = 0; q < 4; q++) {
            int j4 = jg * 4 + q;
            hidT4[e * 17 + (j4 ^ hk)] =
                make_float4(hid[q * 4 + 0], hid[q * 4 + 1], hid[q * 4 + 2], hid[q * 4 + 3]);
        }
    }
    __syncthreads();

    int cg = tid & 15, eg = tid >> 4;
    int e0 = eg * 4, c0 = cg * 8, cgl = cg & 7;
    const float4* hidT4 = (const float4*)sHidT;
    const float4* wbT4  = (const float4*)sWbT;
    int hk0 = ((e0 + 0) >> 1) & 7, hk1 = ((e0 + 1) >> 1) & 7;
    int hk2 = ((e0 + 2) >> 1) & 7, hk3 = ((e0 + 3) >> 1) & 7;
    float acc[4][8];
    #pragma unroll
    for (int i = 0; i < 4; i++)
        #pragma unroll
        for (int cc = 0; cc < 8; cc++) acc[i][cc] = 0.0f;

    for (int jb = 0; jb < 16; ++jb) {
        float4 h0_ = hidT4[(e0 + 0) * 17 + (jb ^ hk0)];
        float4 h1_ = hidT4[(e0 + 1) * 17 + (jb ^ hk1)];
        float4 h2_ = hidT4[(e0 + 2) * 17 + (jb ^ hk2)];
        float4 h3_ = hidT4[(e0 + 3) * 17 + (jb ^ hk3)];
        int wj = jb ^ cgl;
        #pragma unroll
        for (int cc = 0; cc < 8; cc++) {
            float4 wb = wbT4[(c0 + cc) * 16 + wj];
            acc[0][cc] += DOT4(h0_, wb);
            acc[1][cc] += DOT4(h1_, wb);
            acc[2][cc] += DOT4(h2_, wb);
            acc[3][cc] += DOT4(h3_, wb);
        }
    }
    __syncthreads();

    {
        float4* msg4 = (float4*)sMsg;
        #pragma unroll
        for (int i = 0; i < 4; ++i) {
            int e = e0 + i, xk = e & 7;
            msg4[e * 33 + ((2 * cg + 0) ^ xk)] =
                make_float4(acc[i][0], acc[i][1], acc[i][2], acc[i][3]);
            msg4[e * 33 + ((2 * cg + 1) ^ xk)] =
                make_float4(acc[i][4], acc[i][5], acc[i][6], acc[i][7]);
        }
    }
    __syncthreads();

    {
        int q = tid >> 6, c = tid & 63;
        #pragma unroll 4
        for (int i = 0; i < 16; ++i) {
            int e = q * 16 + i;
            if (!sLive[e]) continue;
            int snd = sSnd[e], rcv = sRcv[e];
            float f = feats[(size_t)snd * CC + c];
            float ux = sU[e], uy = sU[64 + e], uz = sU[128 + e];
            int xk = e & 7;
            float w0 = sMsg[e * 132 + (((c >> 2) ^ xk) << 2) + (c & 3)];
            float w1 = sMsg[e * 132 + (((16 + (c >> 2)) ^ xk) << 2) + (c & 3)];
            float m0 = w0 * f, g = w1 * f;
            float* Ar = A + (size_t)rcv * 256;
            atomicAdd(Ar + c,        m0);
            atomicAdd(Ar + 64 + c,   g * ux);
            atomicAdd(Ar + 128 + c,  g * uy);
            atomicAdd(Ar + 192 + c,  g * uz);
        }
    }
}

// ---------------- node update 1: 16 nodes/block, LDS-staged shared weights ----------
__global__ __launch_bounds__(256) void node1(
    const int* __restrict__ elem, const float* __restrict__ A,
    const float* __restrict__ Wmix1, const float* __restrict__ sc1tab,
    const float* __restrict__ Wp1s, const float* __restrict__ Wp1v,
    const float* __restrict__ Wp10, const float* __restrict__ Wp11,
    const float* __restrict__ wrd1,
    float* __restrict__ out0, float* __restrict__ out1, float* __restrict__ d1)
{
    __shared__ float smem[20480];   // 80 KiB exactly
    float* sW0 = smem;
    float* sW1 = smem + 4096;
    float* sP0 = smem + 8192;
    float* sP1 = smem + 12288;
    float* sIn = smem + 16384;      // 16 nodes x 4 rows x 64

    int tid = threadIdx.x, w = tid >> 6, d = tid & 63;
    stage_wT(Wmix1,        sW0, tid);
    stage_wT(Wmix1 + 4096, sW1, tid);
    stage_wT(Wp10,         sP0, tid);
    stage_wT(Wp11,         sP1, tid);
    int nbase = blockIdx.x * 16;
    for (int idx = tid; idx < 4096; idx += 256)
        sIn[idx] = A[(size_t)nbase * 256 + idx];   // (n,4,64) contiguous
    __syncthreads();

    const float4* sIn4 = (const float4*)sIn;
    int rbase = w * 16;   // 4 nodes * 4 rows per wave

    float accs[4] = {0.f, 0.f, 0.f, 0.f};
    float acch[4][3];
    #pragma unroll
    for (int i = 0; i < 4; i++) { acch[i][0] = acch[i][1] = acch[i][2] = 0.f; }

    for (int c4 = 0; c4 < 16; ++c4) {
        float4 w0 = WREAD(sW0, d, c4);
        float4 w1 = WREAD(sW1, d, c4);
        #pragma unroll
        for (int i = 0; i < 4; ++i) {
            int rb = rbase + i * 4;
            float4 a0 = sIn4[(rb + 0) * 16 + c4];
            accs[i] += DOT4(a0, w0);
            float4 a1 = sIn4[(rb + 1) * 16 + c4]; acch[i][0] += DOT4(a1, w1);
            float4 a2 = sIn4[(rb + 2) * 16 + c4]; acch[i][1] += DOT4(a2, w1);
            float4 a3 = sIn4[(rb + 3) * 16 + c4]; acch[i][2] += DOT4(a3, w1);
        }
    }

    int nloc = nbase + w * 4;
    #pragma unroll
    for (int i = 0; i < 4; ++i) {
        int n = nloc + i, e = elem[n];
        float s = accs[i];
        float ws0 = Wp1s[e * 64 + d], ws1 = Wp1s[640 + e * 64 + d], ws2 = Wp1s[1280 + e * 64 + d];
        float wv0 = Wp1v[e * 64 + d], wv1 = Wp1v[640 + e * 64 + d], wv2 = Wp1v[1280 + e * 64 + d];
        float m0 = s * (ws0 + s * (ws1 + s * ws2));
        float gv = wv0 + s * (wv1 + s * wv2);
        int rb = rbase + i * 4;
        sIn[(rb + 0) * 64 + d] = m0;
        sIn[(rb + 1) * 64 + d] = acch[i][0] * gv;
        sIn[(rb + 2) * 64 + d] = acch[i][1] * gv;
        sIn[(rb + 3) * 64 + d] = acch[i][2] * gv;
    }
    // wave-private rows: no block barrier needed (in-order within wave)

    float acc0[4] = {0.f, 0.f, 0.f, 0.f};
    float acc1[4][3];
    #pragma unroll
    for (int i = 0; i < 4; i++) { acc1[i][0] = acc1[i][1] = acc1[i][2] = 0.f; }

    for (int c4 = 0; c4 < 16; ++c4) {
        float4 p0 = WREAD(sP0, d, c4);
        float4 p1 = WREAD(sP1, d, c4);
        #pragma unroll
        for (int i = 0; i < 4; ++i) {
            int rb = rbase + i * 4;
            float4 a0 = sIn4[(rb + 0) * 16 + c4];
            acc0[i] += DOT4(a0, p0);
            float4 a1 = sIn4[(rb + 1) * 16 + c4]; acc1[i][0] += DOT4(a1, p1);
            float4 a2 = sIn4[(rb + 2) * 16 + c4]; acc1[i][1] += DOT4(a2, p1);
            float4 a3 = sIn4[(rb + 3) * 16 + c4]; acc1[i][2] += DOT4(a3, p1);
        }
    }

    float wr = wrd1[d];
    #pragma unroll
    for (int i = 0; i < 4; ++i) {
        int n = nloc + i, e = elem[n];
        out0[(size_t)n * 64 + d] = acc0[i] + sc1tab[e * 64 + d];
        #pragma unroll
        for (int m = 0; m < 3; ++m) {
            float o = acc1[i][m];
            out1[((size_t)n * 3 + m) * 64 + d] = o;
            float v = o * wr;
            v += __shfl_xor(v, 32); v += __shfl_xor(v, 16); v += __shfl_xor(v, 8);
            v += __shfl_xor(v, 4);  v += __shfl_xor(v, 2);  v += __shfl_xor(v, 1);
            if (d == 0) d1[n * 3 + m] = v;
        }
    }
}

// ---------------- node update 2: element-bucketed, 8 nodes/block ---------------------
__global__ __launch_bounds__(256) void node2(
    const int* __restrict__ cnt, const int* __restrict__ offs,
    const int* __restrict__ order,
    const float* __restrict__ A, const float* __restrict__ out1,
    const float* __restrict__ d1,
    const float* __restrict__ Wmix2, const float* __restrict__ Wsc2,
    const float* __restrict__ Wpr2, const float* __restrict__ Wp2,
    const float* __restrict__ Wv, const float* __restrict__ Wg1,
    const float* __restrict__ bg1, const float* __restrict__ Wg2,
    const float* __restrict__ bg2, const float* __restrict__ wrd2,
    const int* __restrict__ batch, const float* __restrict__ chg,
    const float* __restrict__ pos,
    float* __restrict__ total, float* __restrict__ dip)
{
    int e = blockIdx.y;
    int nc = cnt[e];
    int base = blockIdx.x * 8;
    if (base >= nc) return;

    __shared__ float smem[19456];   // 76 KiB
    __shared__ int   sNid[8];
    __shared__ int   sVal[8];
    float* sW0 = smem;               // Wmix2 l0
    float* sW1 = smem + 4096;        // Wmix2 l1
    float* sP  = smem + 8192;        // Wp2
    float* sS  = smem + 12288;       // Wsc2[e]
    float* sWv = smem + 16384;       // 1024 floats, [16][16] f4 XOR
    float* sIn = smem + 17408;       // 8 nodes x 4 rows x 64 = 2048

    int tid = threadIdx.x, w = tid >> 6, d = tid & 63;
    int ob = offs[e];
    if (tid < 8) {
        int q = base + tid;
        sVal[tid] = q < nc;
        sNid[tid] = order[ob + (q < nc ? q : nc - 1)];
    }
    stage_wT(Wmix2,        sW0, tid);
    stage_wT(Wmix2 + 4096, sW1, tid);
    stage_wT(Wp2,          sP,  tid);
    stage_wT(Wsc2 + e * 4096, sS, tid);
    // Wv (64,16) -> sWv4[h*16 + (c4 ^ h)] = (Wv[4c4+0][h],...)
    for (int idx = tid; idx < 1024; idx += 256) {
        int h = idx & 15, c = idx >> 4;
        sWv[(h << 6) + ((((c >> 2) ^ h) << 2) | (c & 3))] = Wv[idx];
    }
    __syncthreads();
    // stage A rows for the 8 nodes (needs sNid -> second barrier)
    for (int idx = tid; idx < 2048; idx += 256) {
        int row = idx >> 6, q = row >> 2, k = row & 3, dd = idx & 63;
        sIn[idx] = A[(size_t)sNid[q] * 256 + k * 64 + dd];
    }
    __syncthreads();

    const float4* sIn4 = (const float4*)sIn;
    int rbase = w * 8;   // 2 nodes * 4 rows per wave

    // ---- stage 1: h2 = A @ Wmix2 -----------------------------------------------------
    float accs[2] = {0.f, 0.f};
    float acch[2][3];
    #pragma unroll
    for (int i = 0; i < 2; i++) acch[i][0] = acch[i][1] = acch[i][2] = 0.f;

    for (int c4 = 0; c4 < 16; ++c4) {
        float4 w0 = WREAD(sW0, d, c4);
        float4 w1 = WREAD(sW1, d, c4);
        #pragma unroll
        for (int i = 0; i < 2; ++i) {
            int rb = rbase + i * 4;
            float4 a0 = sIn4[(rb + 0) * 16 + c4];
            accs[i] += DOT4(a0, w0);
            float4 a1 = sIn4[(rb + 1) * 16 + c4]; acch[i][0] += DOT4(a1, w1);
            float4 a2 = sIn4[(rb + 2) * 16 + c4]; acch[i][1] += DOT4(a2, w1);
            float4 a3 = sIn4[(rb + 3) * 16 + c4]; acch[i][2] += DOT4(a3, w1);
        }
    }

    float wp0 = Wpr2[e * 64 + d], wp1 = Wpr2[640 + e * 64 + d], wp2_ = Wpr2[1280 + e * 64 + d];
    #pragma unroll
    for (int i = 0; i < 2; ++i) {
        float s2 = accs[i];
        float gv2 = wp0 + s2 * (wp1 + s2 * wp2_);
        int rb = rbase + i * 4;
        sIn[(rb + 1) * 64 + d] = acch[i][0] * gv2;
        sIn[(rb + 2) * 64 + d] = acch[i][1] * gv2;
        sIn[(rb + 3) * 64 + d] = acch[i][2] * gv2;
    }

    // ---- stage 2: out2 = t @ Wp2 + out1 @ Wsc2[e] ------------------------------------
    float acc2[2][3];
    #pragma unroll
    for (int i = 0; i < 2; i++) acc2[i][0] = acc2[i][1] = acc2[i][2] = 0.f;
    const float4* o14 = (const float4*)out1;

    for (int c4 = 0; c4 < 16; ++c4) {
        float4 p = WREAD(sP, d, c4);
        float4 s = WREAD(sS, d, c4);
        #pragma unroll
        for (int i = 0; i < 2; ++i) {
            int rb = rbase + i * 4;
            size_t nq = (size_t)sNid[w * 2 + i];
            #pragma unroll
            for (int m = 0; m < 3; ++m) {
                float4 t  = sIn4[(rb + 1 + m) * 16 + c4];
                float4 o1 = o14[(nq * 3 + m) * 16 + c4];   // uniform addr -> broadcast
                acc2[i][m] += DOT4(t, p) + DOT4(o1, s);
            }
        }
    }

    // ---- tail: vh, gates, d2, dip, total ----------------------------------------------
    int m = d >> 4, h = d & 15;          // lanes 0..47 active for vh
    const float4* sWv4 = (const float4*)sWv;
    #pragma unroll
    for (int i = 0; i < 2; ++i) {
        int q = w * 2 + i, rb = rbase + i * 4;
        int n = sNid[q], valid = sVal[q];
        // out2 rows -> LDS (overwrite t rows)
        sIn[(rb + 1) * 64 + d] = acc2[i][0];
        sIn[(rb + 2) * 64 + d] = acc2[i][1];
        sIn[(rb + 3) * 64 + d] = acc2[i][2];

        float vh = 0.f;
        if (d < 48) {
            for (int c4 = 0; c4 < 16; ++c4) {
                float4 o2 = sIn4[(rb + 1 + m) * 16 + c4];
                float4 wv = sWv4[(h << 4) + (c4 ^ h)];
                vh += DOT4(o2, wv);
            }
            sIn[rb * 64 + m * 16 + h] = vh;   // row rb is free
        }
        float* g = sIn + rb * 64;             // scratch row
        if (d < 16) {
            float v0 = g[d], v1 = g[16 + d], v2 = g[32 + d];
            float inv = sqrtf(v0 * v0 + v1 * v1 + v2 * v2 + 1e-12f);
            g[48 + d] = inv;
        }
        if (d < 16) {
            float acc = bg1[d];
            for (int k = 0; k < 16; ++k) acc += g[48 + k] * Wg1[k * 16 + d];
            float s1 = silu_f(acc);
            g[48 + d] = s1;                   // wave-lockstep: reads done
        }
        if (d < 16) {
            float acc = bg2[d];
            for (int k = 0; k < 16; ++k) acc += g[48 + k] * Wg2[k * 16 + d];
            g[48 + d] = acc * wrd2[d];
        }
        if (d < 48) {
            float v = vh * g[48 + h];
            v += __shfl_xor(v, 8, 16); v += __shfl_xor(v, 4, 16);
            v += __shfl_xor(v, 2, 16); v += __shfl_xor(v, 1, 16);
            if (h == 0 && valid) {
                float dv = d1[n * 3 + m] + v;
                dip[n * 3 + m] = dv;
                atomicAdd(&total[batch[n] * 3 + m], dv + chg[n] * pos[n * 3 + m]);
            }
        }
    }
}

extern "C" void kernel_launch(void* const* d_in, const int* in_sizes, int n_in,
                              void* d_out, int out_size, void* d_ws, size_t ws_size,
                              hipStream_t stream) {
    const float* na     = (const float*)d_in[0];
    const float* pos    = (const float*)d_in[1];
    const float* shifts = (const float*)d_in[2];
    const float* chg    = (const float*)d_in[3];
    const int*   eidx   = (const int*)d_in[4];
    const int*   batch  = (const int*)d_in[5];
    const float* Wemb   = (const float*)d_in[7];
    const float* Wr1a   = (const float*)d_in[8];
    const float* Wr1b   = (const float*)d_in[9];
    const float* Wmix1  = (const float*)d_in[10];
    const float* Wsc1   = (const float*)d_in[11];
    const float* Wp1s   = (const float*)d_in[12];
    const float* Wp1v   = (const float*)d_in[13];
    const float* Wp10   = (const float*)d_in[14];
    const float* Wp11   = (const float*)d_in[15];
    const float* wrd1   = (const float*)d_in[16];
    const float* Wr2a   = (const float*)d_in[17];
    const float* Wr2b   = (const float*)d_in[18];
    const float* Wmix2  = (const float*)d_in[19];
    const float* Wsc2   = (const float*)d_in[20];
    const float* Wpr2   = (const float*)d_in[21];
    const float* Wp2    = (const float*)d_in[22];
    const float* Wv     = (const float*)d_in[23];
    const float* Wg1    = (const float*)d_in[24];
    const float* bg1    = (const float*)d_in[25];
    const float* Wg2    = (const float*)d_in[26];
    const float* bg2    = (const float*)d_in[27];
    const float* wrd2   = (const float*)d_in[28];

    float* ws   = (float*)d_ws;
    float* h0   = ws;                         // N*C
    float* A    = h0 + (size_t)NN * CC;       // N*4*C
    float* out0 = A + (size_t)NN * 4 * CC;    // N*C
    float* out1 = out0 + (size_t)NN * CC;     // N*3*C
    float* d1   = out1 + (size_t)NN * 3 * CC; // N*3
    float* sc1t = d1 + (size_t)NN * 3;        // NEL*64
    int*   elem = (int*)(sc1t + NEL * 64);    // N
    int*   cnt  = elem + NN;                  // NEL
    int*   offs = cnt + NEL;                  // NEL
    int*   curs = offs + NEL;                 // NEL
    int*   order= curs + NEL;                 // N

    float* total = (float*)d_out;             // G*3
    float* dip   = total + GG * 3;            // N*3

    hipMemsetAsync(A, 0, (size_t)NN * 4 * CC * sizeof(float), stream);
    hipMemsetAsync(total, 0, (size_t)GG * 3 * sizeof(float), stream);
    hipMemsetAsync(cnt, 0, 3 * NEL * sizeof(int), stream);   // cnt+offs+cursor

    k_h0<<<NN / 4, 256, 0, stream>>>(na, Wemb, h0, elem);
    k_count<<<NN / 256, 256, 0, stream>>>(elem, cnt);
    k_offsets<<<1, 64, 0, stream>>>(cnt, offs, curs);
    k_fill<<<NN / 256, 256, 0, stream>>>(elem, curs, order);
    k_sc1tab<<<NEL, 64, 0, stream>>>(Wemb, Wsc1, sc1t);

    edge_tile<<<EE / 64, 256, 0, stream>>>(h0, pos, shifts, eidx, Wr1a, Wr1b, A);
    node1<<<NN / 16, 256, 0, stream>>>(elem, A, Wmix1, sc1t, Wp1s, Wp1v, Wp10, Wp11,
                                       wrd1, out0, out1, d1);
    hipMemsetAsync(A, 0, (size_t)NN * 4 * CC * sizeof(float), stream);
    edge_tile<<<EE / 64, 256, 0, stream>>>(out0, pos, shifts, eidx, Wr2a, Wr2b, A);
    node2<<<dim3(NN / 8, NEL), 256, 0, stream>>>(cnt, offs, order, A, out1, d1,
                                                 Wmix2, Wsc2, Wpr2, Wp2, Wv, Wg1, bg1,
                                                 Wg2, bg2, wrd2, batch, chg, pos,
                                                 total, dip);
}

// Round 5
// 403.966 us; speedup vs baseline: 1.3396x; 1.3396x over previous
//
#include <hip/hip_runtime.h>
#include <math.h>

#define NN 8192
#define EE 131072
#define CC 64
#define GG 32
#define NEL 10

__device__ __forceinline__ float silu_f(float x) { return x / (1.0f + __expf(-x)); }

// stage a 64x64 row-major matrix W[c][d] into LDS transposed+XOR-swizzled:
// float4 slot (d*16 + (c4 ^ (d&15))) holds (W[4c4+0][d], ..., W[4c4+3][d])
__device__ __forceinline__ void stage_wT(const float* __restrict__ W, float* sWT, int tid) {
    for (int idx = tid; idx < 4096; idx += 256) {
        int d = idx & 63, c = idx >> 6;
        sWT[(d << 6) + ((((c >> 2) ^ (d & 15)) << 2) | (c & 3))] = W[idx];
    }
}
#define WREAD(sWT, d, c4) (((const float4*)(sWT))[((d) << 4) + ((c4) ^ ((d) & 15))])
#define DOT4(a, b) ((a).x * (b).x + (a).y * (b).y + (a).z * (b).z + (a).w * (b).w)

// ---------------- h0 = W_embed[elem] ; elem = argmax(node_attrs) --------------------
__global__ __launch_bounds__(256) void k_h0(const float* __restrict__ na,
                                            const float* __restrict__ Wemb,
                                            float* __restrict__ h0,
                                            int* __restrict__ elem) {
    int n = blockIdx.x * 4 + (threadIdx.x >> 6);
    int d = threadIdx.x & 63;
    float acc = 0.0f;
    float best = -1.0f; int bi = 0;
    #pragma unroll
    for (int k = 0; k < NEL; k++) {
        float a = na[n * NEL + k];
        acc += a * Wemb[k * 64 + d];
        if (a > best) { best = a; bi = k; }
    }
    h0[n * 64 + d] = acc;
    if (d == 0) elem[n] = bi;
}

// ---------------- sc1 lookup table: sc1tab[e] = W_embed[e] @ Wsc1[e] ----------------
__global__ __launch_bounds__(64) void k_sc1tab(const float* __restrict__ Wemb,
                                               const float* __restrict__ Wsc1,
                                               float* __restrict__ tab) {
    int e = blockIdx.x, d = threadIdx.x;
    float acc = 0.0f;
    for (int c = 0; c < 64; c++)
        acc += Wemb[e * 64 + c] * Wsc1[e * 4096 + c * 64 + d];
    tab[e * 64 + d] = acc;
}

// ---------------- element bucketing -------------------------------------------------
__global__ __launch_bounds__(256) void k_count(const int* __restrict__ elem, int* cnt) {
    int n = blockIdx.x * 256 + threadIdx.x;
    atomicAdd(&cnt[elem[n]], 1);
}
__global__ void k_offsets(const int* __restrict__ cnt, int* offs, int* cursor) {
    if (threadIdx.x == 0) {
        int s = 0;
        for (int e = 0; e < NEL; e++) { offs[e] = s; cursor[e] = s; s += cnt[e]; }
    }
}
__global__ __launch_bounds__(256) void k_fill(const int* __restrict__ elem,
                                              int* cursor, int* __restrict__ order) {
    int n = blockIdx.x * 256 + threadIdx.x;
    int p = atomicAdd(&cursor[elem[n]], 1);
    order[p] = n;
}

// ---------------- tiled edge kernel (unchanged) -------------------------------------
__global__ __launch_bounds__(256) void edge_tile(
    const float* __restrict__ feats, const float* __restrict__ pos,
    const float* __restrict__ shifts, const int* __restrict__ eidx,
    const float* __restrict__ Wra, const float* __restrict__ Wrb,
    float* __restrict__ A)
{
    __shared__ float smem[13760];
    __shared__ int   sSnd[64], sRcv[64], sLive[64];
    float* sWaT  = smem;
    float* sWbT  = smem + 512;
    float* sMsg  = smem;
    float* sRb   = smem + 8704;
    float* sHidT = smem + 9216;
    float* sU    = smem + 13568;

    int tid = threadIdx.x;
    int e_base = blockIdx.x * 64;

    if (tid < 64) {
        int e = e_base + tid;
        int snd = eidx[e];
        int rcv = eidx[EE + e];
        float vx = pos[rcv * 3 + 0] - pos[snd * 3 + 0] + shifts[e * 3 + 0];
        float vy = pos[rcv * 3 + 1] - pos[snd * 3 + 1] + shifts[e * 3 + 1];
        float vz = pos[rcv * 3 + 2] - pos[snd * 3 + 2] + shifts[e * 3 + 2];
        float r = sqrtf(vx * vx + vy * vy + vz * vz + 1e-12f);
        float rinv = 1.0f / r;
        float x = r * 0.2f;
        int live = x < 1.0f;
        float pref = 0.0f;
        if (live) {
            float x2 = x * x, x4 = x2 * x2, x5 = x4 * x;
            float env = 1.0f - 21.0f * x5 + 35.0f * x5 * x - 15.0f * x5 * x2;
            pref = 0.632455532033676f * rinv * env;
        }
        float s1, c1;
        __sincosf(0.62831853071795865f * r, &s1, &c1);
        float k2c = 2.0f * c1;
        float sp = 0.0f, sn = s1;
        #pragma unroll
        for (int b = 0; b < 8; b++) {
            sRb[b * 64 + tid] = pref * sn;
            float t = k2c * sn - sp; sp = sn; sn = t;
        }
        sU[tid]       = vx * rinv;
        sU[64 + tid]  = vy * rinv;
        sU[128 + tid] = vz * rinv;
        sSnd[tid] = snd; sRcv[tid] = rcv; sLive[tid] = live;
    }
    for (int idx = tid; idx < 512; idx += 256) {
        int b = idx >> 6, j = idx & 63;
        sWaT[j * 8 + b] = Wra[idx];
    }
    for (int idx = tid; idx < 64 * 128; idx += 256) {
        int j = idx >> 7, c = idx & 127;
        float v = Wrb[j * 256 + c] * (c < 64 ? 0.0625f : 0.10825317547305482f);
        int jb = j >> 2, jl = j & 3;
        int sj = ((jb ^ ((c >> 3) & 7)) << 2) | jl;
        sWbT[c * 64 + sj] = v;
    }
    __syncthreads();

    {
        int e = tid & 63, jg = tid >> 6;
        float rbv[8];
        #pragma unroll
        for (int b = 0; b < 8; b++) rbv[b] = sRb[b * 64 + e];
        const float4* waT4 = (const float4*)sWaT;
        float hid[16];
        #pragma unroll
        for (int jj = 0; jj < 16; jj++) {
            int j = jg * 16 + jj;
            float4 wa0 = waT4[j * 2 + 0];
            float4 wa1 = waT4[j * 2 + 1];
            float acc = rbv[0] * wa0.x + rbv[1] * wa0.y + rbv[2] * wa0.z + rbv[3] * wa0.w
                      + rbv[4] * wa1.x + rbv[5] * wa1.y + rbv[6] * wa1.z + rbv[7] * wa1.w;
            hid[jj] = silu_f(acc);
        }
        float4* hidT4 = (float4*)sHidT;
        int hk = (e >> 1) & 7;
        #pragma unroll
        for (int q = 0; q < 4; q++) {
            int j4 = jg * 4 + q;
            hidT4[e * 17 + (j4 ^ hk)] =
                make_float4(hid[q * 4 + 0], hid[q * 4 + 1], hid[q * 4 + 2], hid[q * 4 + 3]);
        }
    }
    __syncthreads();

    int cg = tid & 15, eg = tid >> 4;
    int e0 = eg * 4, c0 = cg * 8, cgl = cg & 7;
    const float4* hidT4 = (const float4*)sHidT;
    const float4* wbT4  = (const float4*)sWbT;
    int hk0 = ((e0 + 0) >> 1) & 7, hk1 = ((e0 + 1) >> 1) & 7;
    int hk2 = ((e0 + 2) >> 1) & 7, hk3 = ((e0 + 3) >> 1) & 7;
    float acc[4][8];
    #pragma unroll
    for (int i = 0; i < 4; i++)
        #pragma unroll
        for (int cc = 0; cc < 8; cc++) acc[i][cc] = 0.0f;

    for (int jb = 0; jb < 16; ++jb) {
        float4 h0_ = hidT4[(e0 + 0) * 17 + (jb ^ hk0)];
        float4 h1_ = hidT4[(e0 + 1) * 17 + (jb ^ hk1)];
        float4 h2_ = hidT4[(e0 + 2) * 17 + (jb ^ hk2)];
        float4 h3_ = hidT4[(e0 + 3) * 17 + (jb ^ hk3)];
        int wj = jb ^ cgl;
        #pragma unroll
        for (int cc = 0; cc < 8; cc++) {
            float4 wb = wbT4[(c0 + cc) * 16 + wj];
            acc[0][cc] += DOT4(h0_, wb);
            acc[1][cc] += DOT4(h1_, wb);
            acc[2][cc] += DOT4(h2_, wb);
            acc[3][cc] += DOT4(h3_, wb);
        }
    }
    __syncthreads();

    {
        float4* msg4 = (float4*)sMsg;
        #pragma unroll
        for (int i = 0; i < 4; ++i) {
            int e = e0 + i, xk = e & 7;
            msg4[e * 33 + ((2 * cg + 0) ^ xk)] =
                make_float4(acc[i][0], acc[i][1], acc[i][2], acc[i][3]);
            msg4[e * 33 + ((2 * cg + 1) ^ xk)] =
                make_float4(acc[i][4], acc[i][5], acc[i][6], acc[i][7]);
        }
    }
    __syncthreads();

    {
        int q = tid >> 6, c = tid & 63;
        #pragma unroll 4
        for (int i = 0; i < 16; ++i) {
            int e = q * 16 + i;
            if (!sLive[e]) continue;
            int snd = sSnd[e], rcv = sRcv[e];
            float f = feats[(size_t)snd * CC + c];
            float ux = sU[e], uy = sU[64 + e], uz = sU[128 + e];
            int xk = e & 7;
            float w0 = sMsg[e * 132 + (((c >> 2) ^ xk) << 2) + (c & 3)];
            float w1 = sMsg[e * 132 + (((16 + (c >> 2)) ^ xk) << 2) + (c & 3)];
            float m0 = w0 * f, g = w1 * f;
            float* Ar = A + (size_t)rcv * 256;
            atomicAdd(Ar + c,        m0);
            atomicAdd(Ar + 64 + c,   g * ux);
            atomicAdd(Ar + 128 + c,  g * uy);
            atomicAdd(Ar + 192 + c,  g * uz);
        }
    }
}

// ---------------- node update 1: 8 nodes/block (2 per wave), LDS weights ------------
__global__ __launch_bounds__(256) void node1(
    const int* __restrict__ elem, const float* __restrict__ A,
    const float* __restrict__ Wmix1, const float* __restrict__ sc1tab,
    const float* __restrict__ Wp1s, const float* __restrict__ Wp1v,
    const float* __restrict__ Wp10, const float* __restrict__ Wp11,
    const float* __restrict__ wrd1,
    float* __restrict__ out0, float* __restrict__ out1, float* __restrict__ d1)
{
    __shared__ float smem[18432];   // 72 KiB
    float* sW0 = smem;
    float* sW1 = smem + 4096;
    float* sP0 = smem + 8192;
    float* sP1 = smem + 12288;
    float* sIn = smem + 16384;      // 8 nodes x 4 rows x 64

    int tid = threadIdx.x, w = tid >> 6, d = tid & 63;
    stage_wT(Wmix1,        sW0, tid);
    stage_wT(Wmix1 + 4096, sW1, tid);
    stage_wT(Wp10,         sP0, tid);
    stage_wT(Wp11,         sP1, tid);
    int nbase = blockIdx.x * 8;
    for (int idx = tid; idx < 2048; idx += 256)
        sIn[idx] = A[(size_t)nbase * 256 + idx];   // (n,4,64) contiguous
    __syncthreads();

    const float4* sIn4 = (const float4*)sIn;
    int rbase = w * 8;   // 2 nodes * 4 rows per wave
    int nloc = nbase + w * 2;

    // ---- stage 1: h1 = A @ Wmix1 ----------------------------------------------------
    float accs[2] = {0.f, 0.f};
    float acch[2][3];
    #pragma unroll
    for (int i = 0; i < 2; i++) acch[i][0] = acch[i][1] = acch[i][2] = 0.f;

    for (int c4 = 0; c4 < 16; ++c4) {
        float4 w0 = WREAD(sW0, d, c4);
        float4 w1 = WREAD(sW1, d, c4);
        #pragma unroll
        for (int i = 0; i < 2; ++i) {
            int rb = rbase + i * 4;
            float4 a0 = sIn4[(rb + 0) * 16 + c4];
            accs[i] += DOT4(a0, w0);
            float4 a1 = sIn4[(rb + 1) * 16 + c4]; acch[i][0] += DOT4(a1, w1);
            float4 a2 = sIn4[(rb + 2) * 16 + c4]; acch[i][1] += DOT4(a2, w1);
            float4 a3 = sIn4[(rb + 3) * 16 + c4]; acch[i][2] += DOT4(a3, w1);
        }
    }

    // ---- elementwise products (wave-private rows; no block barrier needed) ----------
    #pragma unroll
    for (int i = 0; i < 2; ++i) {
        int n = nloc + i, e = elem[n];
        float s = accs[i];
        float ws0 = Wp1s[e * 64 + d], ws1 = Wp1s[640 + e * 64 + d], ws2 = Wp1s[1280 + e * 64 + d];
        float wv0 = Wp1v[e * 64 + d], wv1 = Wp1v[640 + e * 64 + d], wv2 = Wp1v[1280 + e * 64 + d];
        float m0 = s * (ws0 + s * (ws1 + s * ws2));
        float gv = wv0 + s * (wv1 + s * wv2);
        int rb = rbase + i * 4;
        sIn[(rb + 0) * 64 + d] = m0;
        sIn[(rb + 1) * 64 + d] = acch[i][0] * gv;
        sIn[(rb + 2) * 64 + d] = acch[i][1] * gv;
        sIn[(rb + 3) * 64 + d] = acch[i][2] * gv;
    }

    // ---- stage 2: out0/out1 ----------------------------------------------------------
    float acc0[2] = {0.f, 0.f};
    float acc1[2][3];
    #pragma unroll
    for (int i = 0; i < 2; i++) acc1[i][0] = acc1[i][1] = acc1[i][2] = 0.f;

    for (int c4 = 0; c4 < 16; ++c4) {
        float4 p0 = WREAD(sP0, d, c4);
        float4 p1 = WREAD(sP1, d, c4);
        #pragma unroll
        for (int i = 0; i < 2; ++i) {
            int rb = rbase + i * 4;
            float4 a0 = sIn4[(rb + 0) * 16 + c4];
            acc0[i] += DOT4(a0, p0);
            float4 a1 = sIn4[(rb + 1) * 16 + c4]; acc1[i][0] += DOT4(a1, p1);
            float4 a2 = sIn4[(rb + 2) * 16 + c4]; acc1[i][1] += DOT4(a2, p1);
            float4 a3 = sIn4[(rb + 3) * 16 + c4]; acc1[i][2] += DOT4(a3, p1);
        }
    }

    float wr = wrd1[d];
    #pragma unroll
    for (int i = 0; i < 2; ++i) {
        int n = nloc + i, e = elem[n];
        out0[(size_t)n * 64 + d] = acc0[i] + sc1tab[e * 64 + d];
        #pragma unroll
        for (int m = 0; m < 3; ++m) {
            float o = acc1[i][m];
            out1[((size_t)n * 3 + m) * 64 + d] = o;
            float v = o * wr;
            v += __shfl_xor(v, 32); v += __shfl_xor(v, 16); v += __shfl_xor(v, 8);
            v += __shfl_xor(v, 4);  v += __shfl_xor(v, 2);  v += __shfl_xor(v, 1);
            if (d == 0) d1[n * 3 + m] = v;
        }
    }
}

// ---------------- node update 2: element-bucketed, 8 nodes/block ---------------------
__global__ __launch_bounds__(256) void node2(
    const int* __restrict__ cnt, const int* __restrict__ offs,
    const int* __restrict__ order,
    const float* __restrict__ A, const float* __restrict__ out1,
    const float* __restrict__ d1,
    const float* __restrict__ Wmix2, const float* __restrict__ Wsc2,
    const float* __restrict__ Wpr2, const float* __restrict__ Wp2,
    const float* __restrict__ Wv, const float* __restrict__ Wg1,
    const float* __restrict__ bg1, const float* __restrict__ Wg2,
    const float* __restrict__ bg2, const float* __restrict__ wrd2,
    const int* __restrict__ batch, const float* __restrict__ chg,
    const float* __restrict__ pos,
    float* __restrict__ total, float* __restrict__ dip)
{
    int e = blockIdx.y;
    int nc = cnt[e];
    int base = blockIdx.x * 8;
    if (base >= nc) return;

    __shared__ float smem[19456];   // 76 KiB
    __shared__ int   sNid[8];
    __shared__ int   sVal[8];
    float* sW0 = smem;               // Wmix2 l0
    float* sW1 = smem + 4096;        // Wmix2 l1
    float* sP  = smem + 8192;        // Wp2
    float* sS  = smem + 12288;       // Wsc2[e]
    float* sWv = smem + 16384;       // 1024 floats, [16][16] f4 XOR
    float* sIn = smem + 17408;       // 8 nodes x 4 rows x 64 = 2048

    int tid = threadIdx.x, w = tid >> 6, d = tid & 63;
    int ob = offs[e];
    if (tid < 8) {
        int q = base + tid;
        sVal[tid] = q < nc;
        sNid[tid] = order[ob + (q < nc ? q : nc - 1)];
    }
    stage_wT(Wmix2,        sW0, tid);
    stage_wT(Wmix2 + 4096, sW1, tid);
    stage_wT(Wp2,          sP,  tid);
    stage_wT(Wsc2 + e * 4096, sS, tid);
    for (int idx = tid; idx < 1024; idx += 256) {
        int h = idx & 15, c = idx >> 4;
        sWv[(h << 6) + ((((c >> 2) ^ h) << 2) | (c & 3))] = Wv[idx];
    }
    __syncthreads();
    for (int idx = tid; idx < 2048; idx += 256) {
        int row = idx >> 6, q = row >> 2, k = row & 3, dd = idx & 63;
        sIn[idx] = A[(size_t)sNid[q] * 256 + k * 64 + dd];
    }
    __syncthreads();

    const float4* sIn4 = (const float4*)sIn;
    int rbase = w * 8;   // 2 nodes * 4 rows per wave

    float accs[2] = {0.f, 0.f};
    float acch[2][3];
    #pragma unroll
    for (int i = 0; i < 2; i++) acch[i][0] = acch[i][1] = acch[i][2] = 0.f;

    for (int c4 = 0; c4 < 16; ++c4) {
        float4 w0 = WREAD(sW0, d, c4);
        float4 w1 = WREAD(sW1, d, c4);
        #pragma unroll
        for (int i = 0; i < 2; ++i) {
            int rb = rbase + i * 4;
            float4 a0 = sIn4[(rb + 0) * 16 + c4];
            accs[i] += DOT4(a0, w0);
            float4 a1 = sIn4[(rb + 1) * 16 + c4]; acch[i][0] += DOT4(a1, w1);
            float4 a2 = sIn4[(rb + 2) * 16 + c4]; acch[i][1] += DOT4(a2, w1);
            float4 a3 = sIn4[(rb + 3) * 16 + c4]; acch[i][2] += DOT4(a3, w1);
        }
    }

    float wp0 = Wpr2[e * 64 + d], wp1 = Wpr2[640 + e * 64 + d], wp2_ = Wpr2[1280 + e * 64 + d];
    #pragma unroll
    for (int i = 0; i < 2; ++i) {
        float s2 = accs[i];
        float gv2 = wp0 + s2 * (wp1 + s2 * wp2_);
        int rb = rbase + i * 4;
        sIn[(rb + 1) * 64 + d] = acch[i][0] * gv2;
        sIn[(rb + 2) * 64 + d] = acch[i][1] * gv2;
        sIn[(rb + 3) * 64 + d] = acch[i][2] * gv2;
    }

    float acc2[2][3];
    #pragma unroll
    for (int i = 0; i < 2; i++) acc2[i][0] = acc2[i][1] = acc2[i][2] = 0.f;
    const float4* o14 = (const float4*)out1;

    for (int c4 = 0; c4 < 16; ++c4) {
        float4 p = WREAD(sP, d, c4);
        float4 s = WREAD(sS, d, c4);
        #pragma unroll
        for (int i = 0; i < 2; ++i) {
            int rb = rbase + i * 4;
            size_t nq = (size_t)sNid[w * 2 + i];
            #pragma unroll
            for (int m = 0; m < 3; ++m) {
                float4 t  = sIn4[(rb + 1 + m) * 16 + c4];
                float4 o1 = o14[(nq * 3 + m) * 16 + c4];
                acc2[i][m] += DOT4(t, p) + DOT4(o1, s);
            }
        }
    }

    int m = d >> 4, h = d & 15;
    const float4* sWv4 = (const float4*)sWv;
    #pragma unroll
    for (int i = 0; i < 2; ++i) {
        int q = w * 2 + i, rb = rbase + i * 4;
        int n = sNid[q], valid = sVal[q];
        sIn[(rb + 1) * 64 + d] = acc2[i][0];
        sIn[(rb + 2) * 64 + d] = acc2[i][1];
        sIn[(rb + 3) * 64 + d] = acc2[i][2];

        float vh = 0.f;
        if (d < 48) {
            for (int c4 = 0; c4 < 16; ++c4) {
                float4 o2 = sIn4[(rb + 1 + m) * 16 + c4];
                float4 wv = sWv4[(h << 4) + (c4 ^ h)];
                vh += DOT4(o2, wv);
            }
            sIn[rb * 64 + m * 16 + h] = vh;
        }
        float* g = sIn + rb * 64;
        if (d < 16) {
            float v0 = g[d], v1 = g[16 + d], v2 = g[32 + d];
            g[48 + d] = sqrtf(v0 * v0 + v1 * v1 + v2 * v2 + 1e-12f);
        }
        if (d < 16) {
            float acc = bg1[d];
            for (int k = 0; k < 16; ++k) acc += g[48 + k] * Wg1[k * 16 + d];
            g[48 + d] = silu_f(acc);
        }
        if (d < 16) {
            float acc = bg2[d];
            for (int k = 0; k < 16; ++k) acc += g[48 + k] * Wg2[k * 16 + d];
            g[48 + d] = acc * wrd2[d];
        }
        if (d < 48) {
            float v = vh * g[48 + h];
            v += __shfl_xor(v, 8, 16); v += __shfl_xor(v, 4, 16);
            v += __shfl_xor(v, 2, 16); v += __shfl_xor(v, 1, 16);
            if (h == 0 && valid) {
                float dv = d1[n * 3 + m] + v;
                dip[n * 3 + m] = dv;
                atomicAdd(&total[batch[n] * 3 + m], dv + chg[n] * pos[n * 3 + m]);
            }
        }
    }
}

extern "C" void kernel_launch(void* const* d_in, const int* in_sizes, int n_in,
                              void* d_out, int out_size, void* d_ws, size_t ws_size,
                              hipStream_t stream) {
    const float* na     = (const float*)d_in[0];
    const float* pos    = (const float*)d_in[1];
    const float* shifts = (const float*)d_in[2];
    const float* chg    = (const float*)d_in[3];
    const int*   eidx   = (const int*)d_in[4];
    const int*   batch  = (const int*)d_in[5];
    const float* Wemb   = (const float*)d_in[7];
    const float* Wr1a   = (const float*)d_in[8];
    const float* Wr1b   = (const float*)d_in[9];
    const float* Wmix1  = (const float*)d_in[10];
    const float* Wsc1   = (const float*)d_in[11];
    const float* Wp1s   = (const float*)d_in[12];
    const float* Wp1v   = (const float*)d_in[13];
    const float* Wp10   = (const float*)d_in[14];
    const float* Wp11   = (const float*)d_in[15];
    const float* wrd1   = (const float*)d_in[16];
    const float* Wr2a   = (const float*)d_in[17];
    const float* Wr2b   = (const float*)d_in[18];
    const float* Wmix2  = (const float*)d_in[19];
    const float* Wsc2   = (const float*)d_in[20];
    const float* Wpr2   = (const float*)d_in[21];
    const float* Wp2    = (const float*)d_in[22];
    const float* Wv     = (const float*)d_in[23];
    const float* Wg1    = (const float*)d_in[24];
    const float* bg1    = (const float*)d_in[25];
    const float* Wg2    = (const float*)d_in[26];
    const float* bg2    = (const float*)d_in[27];
    const float* wrd2   = (const float*)d_in[28];

    float* ws   = (float*)d_ws;
    float* h0   = ws;                         // N*C
    float* A    = h0 + (size_t)NN * CC;       // N*4*C
    float* out0 = A + (size_t)NN * 4 * CC;    // N*C
    float* out1 = out0 + (size_t)NN * CC;     // N*3*C
    float* d1   = out1 + (size_t)NN * 3 * CC; // N*3
    float* sc1t = d1 + (size_t)NN * 3;        // NEL*64
    int*   elem = (int*)(sc1t + NEL * 64);    // N
    int*   cnt  = elem + NN;                  // NEL
    int*   offs = cnt + NEL;                  // NEL
    int*   curs = offs + NEL;                 // NEL
    int*   order= curs + NEL;                 // N

    float* total = (float*)d_out;             // G*3
    float* dip   = total + GG * 3;            // N*3

    hipMemsetAsync(A, 0, (size_t)NN * 4 * CC * sizeof(float), stream);
    hipMemsetAsync(total, 0, (size_t)GG * 3 * sizeof(float), stream);
    hipMemsetAsync(cnt, 0, 3 * NEL * sizeof(int), stream);

    k_h0<<<NN / 4, 256, 0, stream>>>(na, Wemb, h0, elem);
    k_count<<<NN / 256, 256, 0, stream>>>(elem, cnt);
    k_offsets<<<1, 64, 0, stream>>>(cnt, offs, curs);
    k_fill<<<NN / 256, 256, 0, stream>>>(elem, curs, order);
    k_sc1tab<<<NEL, 64, 0, stream>>>(Wemb, Wsc1, sc1t);

    edge_tile<<<EE / 64, 256, 0, stream>>>(h0, pos, shifts, eidx, Wr1a, Wr1b, A);
    node1<<<NN / 8, 256, 0, stream>>>(elem, A, Wmix1, sc1t, Wp1s, Wp1v, Wp10, Wp11,
                                      wrd1, out0, out1, d1);
    hipMemsetAsync(A, 0, (size_t)NN * 4 * CC * sizeof(float), stream);
    edge_tile<<<EE / 64, 256, 0, stream>>>(out0, pos, shifts, eidx, Wr2a, Wr2b, A);
    node2<<<dim3(NN / 8, NEL), 256, 0, stream>>>(cnt, offs, order, A, out1, d1,
                                                 Wmix2, Wsc2, Wpr2, Wp2, Wv, Wg1, bg1,
                                                 Wg2, bg2, wrd2, batch, chg, pos,
                                                 total, dip);
}